// Round 4
// baseline (326.654 us; speedup 1.0000x reference)
//
#include <hip/hip_runtime.h>

#define HW_   (512 * 512)   // pixels per image
#define NIMG  8
#define NC    19            // classes
#define NSP   2048          // superpixels per image
#define TC    20            // target row stride (C+1, last col sliced off)
#define NROWS (NIMG * NSP)  // 16384 target rows
#define TILE  4096          // pixels per block-tile (16 per thread)
#define NTILE (NIMG * HW_ / TILE)   // 512 tiles
#define NBLK  512           // 2 blocks/CU -> ALL co-resident (spin-safe)
#define NGRP  16            // completion-ticket groups (32 blocks each)
#define GSIZE (NBLK / NGRP)
#define PBLK  64            // blocks that also build the bitmask table

typedef float vf4 __attribute__((ext_vector_type(4)));
typedef int   vi4 __attribute__((ext_vector_type(4)));

// d_ws layout (first 1088 B zeroed by hipMemsetAsync each launch):
//   [0]    flag (uint)       spmask width: 1 -> 4-byte, 0 -> 1-byte
//   [4]    st   (uint)       super ticket
//   [8]    pd   (uint)       prep-done counter (0..64)
//   [64]   gt[NGRP] uints, stride 16 (64 B apart -> no same-line RMWs)
//   [1088] pl[NBLK] float    per-block loss partials
//   [3136] pc[NBLK] uint     per-block count partials
//   [5184] bmt[NROWS] uint   per-(image,superpixel) multi-hot bitmask

// ---------------------------------------------------------------------------
// Single fused kernel, CLASS-OUTER restructure.
// Rationale: R1/R2/R3 all pinned at 620-730 GB/s HBM read regardless of
// occupancy/ordering. Their shared trait: per tile, 19 chunks exactly 1 MB
// apart -> all 19 hit the same DRAM channel/bank set with different rows
// (channel bits = low addr bits), and chip-wide the ~20k interleaved stream
// heads make every 256-B granule pay a row activate (~tRC) -> ~100-140 us
// for 176 MB. Fix: classes OUTER, pixels inner. softmax denominator AND
// numerator are class-sums, so per-pixel (se, ts) accumulators stream over
// c. Each class visit now reads 16 KB CONTIGUOUS per block (4-KB runs per
// wave instruction) -> row-hit-dominated DRAM.
//   Phase P (blocks 0..63): bitmask build (20 KB LDS-staged, coalesced),
//     device-scope release on pd. Width detection by block 1.
//   Main: spin on pd (co-resident by capacity: 512 blocks, 2/CU), stage
//     this image's 8-KB bitmask table to LDS, gather per-pixel bitmasks,
//     load spmask, then the 19-class A/B-pipelined accumulation, NLL, and
//     the hierarchical-ticket reduction.
// Per-pixel FP order (ascending classes) is bitwise-identical to R1/R3.
// ---------------------------------------------------------------------------
__global__ __launch_bounds__(256, 2) void mcce_fused(
    const float* __restrict__ x,      // (N, C, H*W)
    const float* __restrict__ tgt,    // (N, NSP, TC)
    const int*   __restrict__ sp,     // (N, H*W)
    const void*  __restrict__ spm,    // (N, H*W) mask, 1B or 4B elements
    unsigned int* __restrict__ flag,
    unsigned int* __restrict__ st,
    unsigned int* __restrict__ pd,
    unsigned int* __restrict__ gt,
    float* __restrict__ pl, unsigned int* __restrict__ pc,
    unsigned int* __restrict__ bmt,
    float* __restrict__ out) {

    __shared__ vf4 stage[1280];          // 20 KB: prep staging (blocks 0..63)
    __shared__ unsigned int bmtab[NSP];  // 8 KB: this image's bitmasks
    __shared__ float sL[4];
    __shared__ unsigned int sC[4];

    int b    = blockIdx.x;
    int t    = threadIdx.x;
    int wave = t >> 6;
    int lane = t & 63;

    // ---------------- Phase P: build bitmask table ----------------
    if (b < PBLK) {
        if (b == 1 && t < 64) {          // one wave: width detection
            const unsigned int* w = (const unsigned int*)spm;
            unsigned int nonlow = 0, upper = 0;
            for (int i = t; i < 1024; i += 64) {
                unsigned int v = w[i];
                nonlow |= (v & 0xFEFEFEFEu);
                upper  |= (v & 0xFFFFFF00u);
            }
            unsigned long long b1 = __ballot(nonlow != 0);
            unsigned long long b2 = __ballot(upper != 0);
            if (t == 0)
                *flag = ((b1 == 0ull) && (b2 != 0ull)) ? 0u : 1u;
        }
        // 256 rows (20 KB) staged fully coalesced, then row scan from LDS.
        const vf4* src = (const vf4*)(tgt + (size_t)b * (256 * TC));
#pragma unroll
        for (int k = 0; k < 5; ++k) stage[t + k * 256] = src[t + k * 256];
        __syncthreads();
        const float* sf = (const float*)stage;
        unsigned int m = 0;
        int base = t * TC;
#pragma unroll
        for (int c = 0; c < NC; ++c)
            m |= (sf[base + c] != 0.0f ? 1u : 0u) << c;
        bmt[b * 256 + t] = m;
        __threadfence();                 // device-scope order for bmt stores
        __syncthreads();
        if (t == 0)
            __hip_atomic_fetch_add(pd, 1u, __ATOMIC_RELEASE,
                                   __HIP_MEMORY_SCOPE_AGENT);
    }

    // ---------------- Main phase ----------------
    int n  = b >> 6;                     // 64 tiles per image
    int tp = (b & 63) * TILE;            // tile base pixel within image
    int wp = tp + wave * 1024;           // this wave's 1024-px sub-tile

    // sp indices: independent of prep, issue before the spin.
    const int* spw = sp + (size_t)n * HW_ + wp;
    vi4 s4[4];
#pragma unroll
    for (int j = 0; j < 4; ++j)
        s4[j] = ((const vi4*)spw)[lane + j * 64];

    // Wait for the bitmask table (all 512 blocks co-resident by capacity).
    if (t == 0) {
        while (__hip_atomic_load(pd, __ATOMIC_ACQUIRE,
                                 __HIP_MEMORY_SCOPE_AGENT) < PBLK)
            __builtin_amdgcn_s_sleep(8);
    }
    __syncthreads();
    unsigned int flagv = *flag;          // wave-uniform

    // Stage this image's bitmask table into LDS (8 coalesced vi4 loads).
    const vi4* btv = (const vi4*)(bmt + (size_t)n * NSP);
    ((vi4*)bmtab)[t]       = btv[t];
    ((vi4*)bmtab)[t + 256] = btv[t + 256];
    __syncthreads();

    // Per-pixel bitmasks from LDS (random addr ~2-way conflicts, free).
    unsigned int bv[4][4];
#pragma unroll
    for (int j = 0; j < 4; ++j) {
        bv[j][0] = bmtab[s4[j].x]; bv[j][1] = bmtab[s4[j].y];
        bv[j][2] = bmtab[s4[j].z]; bv[j][3] = bmtab[s4[j].w];
    }

    // spmask (wave-uniform width branch); 4-bit valid-mask per j-group.
    int mkb[4];
    size_t mbase = (size_t)n * HW_ + wp;
    if (flagv) {
#pragma unroll
        for (int j = 0; j < 4; ++j) {
            vi4 m = *(const vi4*)((const int*)spm + mbase + j * 256 + lane * 4);
            mkb[j] = (m.x != 0 ? 1 : 0) | (m.y != 0 ? 2 : 0) |
                     (m.z != 0 ? 4 : 0) | (m.w != 0 ? 8 : 0);
        }
    } else {
#pragma unroll
        for (int j = 0; j < 4; ++j) {
            unsigned int mw = *(const unsigned int*)
                              ((const unsigned char*)spm + mbase + j * 256 + lane * 4);
            mkb[j] = ((mw        & 0xFFu) ? 1 : 0) | (((mw >> 8)  & 0xFFu) ? 2 : 0) |
                     (((mw >> 16) & 0xFFu) ? 4 : 0) | (((mw >> 24) & 0xFFu) ? 8 : 0);
        }
    }

    // ---- class-outer streaming accumulation, 2-deep A/B pipeline ----
    // Per class: 4 consecutive dwordx4 per wave = 4-KB contiguous run;
    // 16-KB contiguous per block. No 1-MB-stride bursts anywhere.
    const float* xw = x + (size_t)n * NC * HW_ + wp;   // class-0 base
    vf4 A[4], B[4];
    vf4 se[4] = {{0,0,0,0},{0,0,0,0},{0,0,0,0},{0,0,0,0}};
    vf4 ts[4] = {{0,0,0,0},{0,0,0,0},{0,0,0,0},{0,0,0,0}};

#define LDC(R, c) { const vf4* p_ = (const vf4*)(xw + (size_t)(c) * HW_);      \
    _Pragma("unroll") for (int j_ = 0; j_ < 4; ++j_) R[j_] = p_[lane + j_*64]; }

#define PRC(R, c) { _Pragma("unroll") for (int j_ = 0; j_ < 4; ++j_) {         \
    vf4 e_;                                                                    \
    e_.x = __expf(R[j_].x); e_.y = __expf(R[j_].y);                            \
    e_.z = __expf(R[j_].z); e_.w = __expf(R[j_].w);                            \
    se[j_].x += e_.x; se[j_].y += e_.y; se[j_].z += e_.z; se[j_].w += e_.w;    \
    ts[j_].x += ((bv[j_][0] >> (c)) & 1) ? e_.x : 0.0f;                        \
    ts[j_].y += ((bv[j_][1] >> (c)) & 1) ? e_.y : 0.0f;                        \
    ts[j_].z += ((bv[j_][2] >> (c)) & 1) ? e_.z : 0.0f;                        \
    ts[j_].w += ((bv[j_][3] >> (c)) & 1) ? e_.w : 0.0f; } }

    LDC(A, 0)
#pragma unroll
    for (int p = 0; p < 9; ++p) {        // classes 2p, 2p+1; preload 2p+2
        LDC(B, 2 * p + 1)
        PRC(A, 2 * p)
        LDC(A, 2 * p + 2)                // p=8 -> class 18
        PRC(B, 2 * p + 1)
    }
    PRC(A, 18)

#undef LDC
#undef PRC

    // ---- per-lane NLL over 16 pixels ----
    float lsum = 0.0f;
    unsigned int lcnt = 0;
#pragma unroll
    for (int j = 0; j < 4; ++j) {
        if ((mkb[j] & 1) && bv[j][0]) { lsum -= __logf(ts[j].x / se[j].x + 1e-8f); ++lcnt; }
        if ((mkb[j] & 2) && bv[j][1]) { lsum -= __logf(ts[j].y / se[j].y + 1e-8f); ++lcnt; }
        if ((mkb[j] & 4) && bv[j][2]) { lsum -= __logf(ts[j].z / se[j].z + 1e-8f); ++lcnt; }
        if ((mkb[j] & 8) && bv[j][3]) { lsum -= __logf(ts[j].w / se[j].w + 1e-8f); ++lcnt; }
    }

    // ---- wave-64 shuffle reduction -> LDS block reduction ----
    for (int o = 32; o > 0; o >>= 1) {
        lsum += __shfl_down(lsum, o);
        lcnt += __shfl_down(lcnt, o);
    }
    if ((t & 63) == 0) { sL[wave] = lsum; sC[wave] = lcnt; }
    __syncthreads();

    if (t == 0) {
        float        L = sL[0] + sL[1] + sL[2] + sL[3];
        unsigned int C = sC[0] + sC[1] + sC[2] + sC[3];
        __hip_atomic_store(&pl[b], L, __ATOMIC_RELAXED, __HIP_MEMORY_SCOPE_AGENT);
        __hip_atomic_store(&pc[b], C, __ATOMIC_RELAXED, __HIP_MEMORY_SCOPE_AGENT);
        // Hierarchical tickets: 16 groups of 32 (64-B-padded lines), then
        // one super ticket -> max ~32 same-line RMWs anywhere.
        unsigned int g = (unsigned int)b / GSIZE;
        unsigned int isLast = 0u;
        unsigned int tk = __hip_atomic_fetch_add(&gt[g * 16], 1u,
                              __ATOMIC_ACQ_REL, __HIP_MEMORY_SCOPE_AGENT);
        if (tk == (unsigned int)(GSIZE - 1)) {
            unsigned int s = __hip_atomic_fetch_add(st, 1u,
                                 __ATOMIC_ACQ_REL, __HIP_MEMORY_SCOPE_AGENT);
            isLast = (s == NGRP - 1) ? 1u : 0u;
        }
        sC[0] = isLast;                  // reuse LDS as broadcast
    }
    __syncthreads();

    // Last block: reduce the 512 partials and write the scalar.
    if (sC[0]) {
        float        L = 0.0f;
        unsigned int C = 0u;
        for (int i = t; i < NBLK; i += 256) {
            L += __hip_atomic_load(&pl[i], __ATOMIC_RELAXED, __HIP_MEMORY_SCOPE_AGENT);
            C += __hip_atomic_load(&pc[i], __ATOMIC_RELAXED, __HIP_MEMORY_SCOPE_AGENT);
        }
        for (int o = 32; o > 0; o >>= 1) {
            L += __shfl_down(L, o);
            C += __shfl_down(C, o);
        }
        __syncthreads();                 // LDS reuse barrier
        if ((t & 63) == 0) { sL[wave] = L; sC[wave] = C; }
        __syncthreads();
        if (t == 0) {
            L = sL[0] + sL[1] + sL[2] + sL[3];
            C = sC[0] + sC[1] + sC[2] + sC[3];
            out[0] = L / (float)(1u + C);
        }
    }
}

extern "C" void kernel_launch(void* const* d_in, const int* in_sizes, int n_in,
                              void* d_out, int out_size, void* d_ws, size_t ws_size,
                              hipStream_t stream) {
    const float* x   = (const float*)d_in[0];   // inputs (8,19,512,512) f32
    const float* tgt = (const float*)d_in[1];   // targets (8,2048,20) f32
    const int*   sp  = (const int*)d_in[2];     // superpixels (8,512,512) i32
    const void*  spm = d_in[3];                 // spmasks (8,512,512), width detected

    unsigned int* flag = (unsigned int*)d_ws;
    unsigned int* st   = (unsigned int*)((char*)d_ws + 4);
    unsigned int* pd   = (unsigned int*)((char*)d_ws + 8);
    unsigned int* gt   = (unsigned int*)((char*)d_ws + 64);
    float*        pl   = (float*)((char*)d_ws + 1088);
    unsigned int* pc   = (unsigned int*)((char*)d_ws + 3136);
    unsigned int* bmt  = (unsigned int*)((char*)d_ws + 5184);

    // Zero flag/st/pd/gt (first 1088 B). Stream-ordered, graph-capturable.
    hipMemsetAsync(d_ws, 0, 1088, stream);

    mcce_fused<<<NBLK, 256, 0, stream>>>(x, tgt, sp, spm, flag, st, pd, gt,
                                         pl, pc, bmt, (float*)d_out);
}